// Round 1
// baseline (20450.923 us; speedup 1.0000x reference)
//
#include <hip/hip_runtime.h>

// B=256, D=128, T=512, E=128, H=512, WH=512, WIN=64
typedef __attribute__((ext_vector_type(8))) short s8v;
typedef __attribute__((ext_vector_type(4))) float f4v;

#define MFMA16(a, b, c) __builtin_amdgcn_mfma_f32_16x16x32_bf16((a), (b), (c), 0, 0, 0)

__device__ __forceinline__ unsigned short f2bf(float f) {
  unsigned u = __float_as_uint(f);
  return (unsigned short)((u + 0x7fffu + ((u >> 16) & 1u)) >> 16);
}

// ---------- fp32 -> bf16 conversion (vectorized by 4) ----------
__global__ void cvt4_kernel(const float* __restrict__ in, unsigned short* __restrict__ out, int n4) {
  int i = blockIdx.x * blockDim.x + threadIdx.x;
  if (i >= n4) return;
  float4 v = ((const float4*)in)[i];
  ushort4 o;
  o.x = f2bf(v.x); o.y = f2bf(v.y); o.z = f2bf(v.z); o.w = f2bf(v.w);
  ((ushort4*)out)[i] = o;
}

// ---------- slow_input = [context | e] as bf16 (256 x 640) ----------
__global__ void build_slow_kernel(const float* __restrict__ context, const float* __restrict__ e,
                                  unsigned short* __restrict__ out) {
  int i = blockIdx.x * blockDim.x + threadIdx.x;
  if (i >= 256 * 640) return;
  int b = i / 640, c = i - b * 640;
  float v = (c < 512) ? context[b * 512 + c] : e[b * 128 + (c - 512)];
  out[i] = f2bf(v);
}

// ---------- generic GEMM: C[M][N] = act(A[M][K] @ B[N][K]^T + bias), bf16 in fp32 out ----------
// grid (M/64, N/64), block 256. K % 32 == 0.
template <int RELU>
__global__ __launch_bounds__(256) void gemm_bt(const unsigned short* __restrict__ A,
                                               const unsigned short* __restrict__ B,
                                               const float* __restrict__ bias, float* __restrict__ C,
                                               int M, int N, int K) {
  __shared__ unsigned short As[64][48];  // +16 pad keeps 16B alignment per row
  __shared__ unsigned short Bs[64][48];
  int tid = threadIdx.x;
  int lane = tid & 63, w = tid >> 6;
  int m = lane & 15, q = lane >> 4;
  int row0 = blockIdx.x * 64, col0 = blockIdx.y * 64;
  int sr = tid >> 2, sk = (tid & 3) * 8;
  const unsigned short* Ap = A + (size_t)(row0 + sr) * K + sk;
  const unsigned short* Bp = B + (size_t)(col0 + sr) * K + sk;
  f4v acc[4];
#pragma unroll
  for (int nt = 0; nt < 4; nt++) acc[nt] = (f4v){0.f, 0.f, 0.f, 0.f};

  for (int k0 = 0; k0 < K; k0 += 32) {
    *(uint4*)&As[sr][sk] = *(const uint4*)(Ap + k0);
    *(uint4*)&Bs[sr][sk] = *(const uint4*)(Bp + k0);
    __syncthreads();
    s8v a = *(const s8v*)&As[w * 16 + m][q * 8];
#pragma unroll
    for (int nt = 0; nt < 4; nt++) {
      s8v bb = *(const s8v*)&Bs[nt * 16 + m][q * 8];
      acc[nt] = MFMA16(a, bb, acc[nt]);
    }
    __syncthreads();
  }
#pragma unroll
  for (int nt = 0; nt < 4; nt++) {
    int c = col0 + nt * 16 + m;
    float bv = bias[c];
#pragma unroll
    for (int i = 0; i < 4; i++) {
      int r = row0 + w * 16 + q * 4 + i;
      float v = acc[nt][i] + bv;
      if (RELU) v = v > 0.f ? v : 0.f;
      C[(size_t)r * N + c] = v;
    }
  }
}

// ---------- phase C: the GRU scan ----------
// grid 16 (one WG per 16 batch rows), block 512 (8 waves; wave w owns gate cols [w*64, w*64+64)).
// gi: fp32 [256][1536] (includes b_ih). Whh: bf16 [1536][512]. bhh: fp32 [1536].
// Hall: bf16 [256][512(T)][512(H)] — stores h_{t+1} at index t.
__global__ __launch_bounds__(512, 2) void gru_scan(const float* __restrict__ gi,
                                                   const unsigned short* __restrict__ Whh,
                                                   const float* __restrict__ bhh,
                                                   unsigned short* __restrict__ Hall) {
  __shared__ unsigned short hs[16][520];  // +8 elem pad: conflict-free b128 A-frag reads
  int tid = threadIdx.x;
  int lane = tid & 63, w = tid >> 6;
  int m = lane & 15, q = lane >> 4;
  int b0 = blockIdx.x * 16;

  // zero h in LDS
  for (int i = tid; i < 16 * 520; i += 512) ((unsigned short*)hs)[i] = 0;

  // Preload time-invariant gate inputs (gi + folded b_hh) in C/D layout, and W_hh row pointers.
  float gir[4][4], giz[4][4], gin[4][4], bhn[4];
  const unsigned short *wr[4], *wz[4], *wn[4];
#pragma unroll
  for (int g = 0; g < 4; g++) {
    int cr = w * 64 + g * 16 + m;  // r-gate column in [0,512)
    float br = bhh[cr], bz = bhh[cr + 512];
    bhn[g] = bhh[cr + 1024];
#pragma unroll
    for (int i = 0; i < 4; i++) {
      int rowb = b0 + q * 4 + i;
      const float* gp = gi + (size_t)rowb * 1536 + cr;
      gir[g][i] = gp[0] + br;
      giz[g][i] = gp[512] + bz;
      gin[g][i] = gp[1024];
    }
    size_t ko = (size_t)q * 8;
    wr[g] = Whh + (size_t)cr * 512 + ko;
    wz[g] = Whh + (size_t)(cr + 512) * 512 + ko;
    wn[g] = Whh + (size_t)(cr + 1024) * 512 + ko;
  }
  float hreg[4][4];
#pragma unroll
  for (int g = 0; g < 4; g++)
#pragma unroll
    for (int i = 0; i < 4; i++) hreg[g][i] = 0.f;

  __syncthreads();

  float hnew[4][4];
#pragma unroll 1
  for (int t = 0; t < 512; t++) {
    // A-fragments: full h tile (16 x 512) -> 16 b128 reads, conflict-free
    s8v af[16];
#pragma unroll
    for (int kc = 0; kc < 16; kc++) af[kc] = *(const s8v*)&hs[m][kc * 32 + q * 8];

#pragma unroll
    for (int g = 0; g < 4; g++) {
      f4v ar = {gir[g][0], gir[g][1], gir[g][2], gir[g][3]};
      f4v az = {giz[g][0], giz[g][1], giz[g][2], giz[g][3]};
      f4v an = {bhn[g], bhn[g], bhn[g], bhn[g]};
#pragma unroll
      for (int kc = 0; kc < 16; kc++) {
        s8v br_ = *(const s8v*)(wr[g] + kc * 32);
        ar = MFMA16(af[kc], br_, ar);
        s8v bz_ = *(const s8v*)(wz[g] + kc * 32);
        az = MFMA16(af[kc], bz_, az);
        s8v bn_ = *(const s8v*)(wn[g] + kc * 32);
        an = MFMA16(af[kc], bn_, an);
      }
      // gates (fp32): r=sig(i_r+h_r), z=sig(i_z+h_z), n=tanh(i_n + r*h_n)
#pragma unroll
      for (int i = 0; i < 4; i++) {
        float r = 1.f / (1.f + __expf(-ar[i]));
        float zg = 1.f / (1.f + __expf(-az[i]));
        float x = gin[g][i] + r * an[i];
        float ex = __expf(2.f * x);
        float n = 1.f - 2.f / (ex + 1.f);
        float hn = (1.f - zg) * n + zg * hreg[g][i];
        hreg[g][i] = hn;
        hnew[g][i] = hn;
      }
    }
    __syncthreads();  // all reads of h_t done
#pragma unroll
    for (int g = 0; g < 4; g++) {
      int c = w * 64 + g * 16 + m;
#pragma unroll
      for (int i = 0; i < 4; i++) hs[q * 4 + i][c] = f2bf(hnew[g][i]);
    }
    __syncthreads();  // h_{t+1} visible
    // copy h_{t+1} -> Hall[b][t][:], coalesced 16B chunks
    {
      int mm = tid >> 5, c0 = tid & 31;
      uint4 v0 = *(const uint4*)&hs[mm][c0 * 8];
      uint4 v1 = *(const uint4*)&hs[mm][(c0 + 32) * 8];
      size_t base = ((size_t)(b0 + mm) * 512 + t) * 512;
      *(uint4*)&Hall[base + c0 * 8] = v0;
      *(uint4*)&Hall[base + (c0 + 32) * 8] = v1;
    }
  }
}

// ---------- phase D+E fused: inc = Hall @ Wfc^T + bfc; out[b,d,t] = zp0 + cumsum_t(inc) ----------
// grid 256 (one WG per batch row), block 256 (4 waves; wave w owns d-tiles 2w, 2w+1).
__global__ __launch_bounds__(256) void fc_scan(const unsigned short* __restrict__ Hall,
                                               const unsigned short* __restrict__ Wfc,
                                               const float* __restrict__ bfc,
                                               const float* __restrict__ zctx,
                                               float* __restrict__ out) {
  __shared__ unsigned short hs[16][520];
  int tid = threadIdx.x;
  int lane = tid & 63, w = tid >> 6;
  int m = lane & 15, q = lane >> 4;
  int b = blockIdx.x;

  // W_fc B-fragments persistent in registers (2 tiles x 16 kc x 16B)
  s8v wf[2][16];
  float bf_r[2], carry[2];
#pragma unroll
  for (int j = 0; j < 2; j++) {
    int d = (2 * w + j) * 16 + m;
#pragma unroll
    for (int kc = 0; kc < 16; kc++)
      wf[j][kc] = *(const s8v*)(Wfc + (size_t)d * 512 + kc * 32 + q * 8);
    bf_r[j] = bfc[d];
    carry[j] = zctx[((size_t)b * 128 + d) * 64 + 63];  // zp0 = z_ctx[:, :, -1]
  }

#pragma unroll 1
  for (int chunk = 0; chunk < 32; chunk++) {
    int t0 = chunk * 16;
    // stage 16 timesteps of h into LDS (coalesced)
    {
      int mm = tid >> 4, ci = (tid & 15) * 4;
      const unsigned short* src = Hall + ((size_t)b * 512 + t0 + mm) * 512 + ci * 8;
#pragma unroll
      for (int o = 0; o < 4; o++) {
        uint4 v = *(const uint4*)(src + o * 8);
        *(uint4*)&hs[mm][(ci + o) * 8] = v;
      }
    }
    __syncthreads();
    s8v af[16];
#pragma unroll
    for (int kc = 0; kc < 16; kc++) af[kc] = *(const s8v*)&hs[m][kc * 32 + q * 8];
    f4v acc[2];
    acc[0] = (f4v){0.f, 0.f, 0.f, 0.f};
    acc[1] = (f4v){0.f, 0.f, 0.f, 0.f};
#pragma unroll
    for (int kc = 0; kc < 16; kc++) {
      acc[0] = MFMA16(af[kc], wf[0][kc], acc[0]);
      acc[1] = MFMA16(af[kc], wf[1][kc], acc[1]);
    }
    __syncthreads();  // before next chunk overwrites hs

#pragma unroll
    for (int j = 0; j < 2; j++) {
      float s0 = acc[j][0] + bf_r[j];
      float s1 = s0 + acc[j][1] + bf_r[j];
      float s2 = s1 + acc[j][2] + bf_r[j];
      float s3 = s2 + acc[j][3] + bf_r[j];
      float tot = s3;
      float incl = tot;
      float u = __shfl_up(incl, 16, 64);
      if (q >= 1) incl += u;
      u = __shfl_up(incl, 32, 64);
      if (q >= 2) incl += u;
      float excl = incl - tot;
      float add = excl + carry[j];
      int d = (2 * w + j) * 16 + m;
      float4 o4 = make_float4(s0 + add, s1 + add, s2 + add, s3 + add);
      *(float4*)(out + ((size_t)b * 128 + d) * 512 + t0 + q * 4) = o4;
      float chunktot = __shfl(incl, 48 + m, 64);  // inclusive at q=3, same d
      carry[j] += chunktot;
    }
  }
}

extern "C" void kernel_launch(void* const* d_in, const int* in_sizes, int n_in,
                              void* d_out, int out_size, void* d_ws, size_t ws_size,
                              hipStream_t stream) {
  const float* z_ctx = (const float*)d_in[0];   // (256,128,64)
  const float* e     = (const float*)d_in[4];   // (256,128)
  const float* W_enc = (const float*)d_in[5];   // (512, 8192)
  const float* b_enc = (const float*)d_in[6];   // (512)
  const float* W_ih  = (const float*)d_in[7];   // (1536, 640)
  const float* W_hh  = (const float*)d_in[8];   // (1536, 512)
  const float* b_ih  = (const float*)d_in[9];   // (1536)
  const float* b_hh  = (const float*)d_in[10];  // (1536)
  const float* W_fc  = (const float*)d_in[11];  // (128, 512)
  const float* b_fc  = (const float*)d_in[12];  // (128)
  float* out = (float*)d_out;                   // (256,128,512)

  char* ws = (char*)d_ws;
  const size_t OFF_WENC = 0;          // 512*8192*2  = 8388608
  const size_t OFF_ZCTX = 8388608;    // 256*8192*2  = 4194304
  const size_t OFF_WIH  = 12582912;   // 1536*640*2  = 1966080
  const size_t OFF_WHH  = 14548992;   // 1536*512*2  = 1572864
  const size_t OFF_WFC  = 16121856;   // 128*512*2   = 131072
  const size_t OFF_CTX  = 16252928;   // 256*512*4   = 524288
  const size_t OFF_SLOW = 16777216;   // 256*640*2   = 327680
  const size_t OFF_GI   = 17104896;   // 256*1536*4  = 1572864
  const size_t OFF_HALL = 18677760;   // 256*512*512*2 = 134217728
  const size_t NEED = OFF_HALL + 134217728ull;
  if (ws_size < NEED) return;

  unsigned short* Wenc_bf = (unsigned short*)(ws + OFF_WENC);
  unsigned short* zctx_bf = (unsigned short*)(ws + OFF_ZCTX);
  unsigned short* Wih_bf  = (unsigned short*)(ws + OFF_WIH);
  unsigned short* Whh_bf  = (unsigned short*)(ws + OFF_WHH);
  unsigned short* Wfc_bf  = (unsigned short*)(ws + OFF_WFC);
  float* context          = (float*)(ws + OFF_CTX);
  unsigned short* slow_bf = (unsigned short*)(ws + OFF_SLOW);
  float* gi               = (float*)(ws + OFF_GI);
  unsigned short* Hall    = (unsigned short*)(ws + OFF_HALL);

  // conversions
  cvt4_kernel<<<4096, 256, 0, stream>>>(W_enc, Wenc_bf, 512 * 8192 / 4);
  cvt4_kernel<<<2048, 256, 0, stream>>>(z_ctx, zctx_bf, 256 * 8192 / 4);
  cvt4_kernel<<<960, 256, 0, stream>>>(W_ih, Wih_bf, 1536 * 640 / 4);
  cvt4_kernel<<<768, 256, 0, stream>>>(W_hh, Whh_bf, 1536 * 512 / 4);
  cvt4_kernel<<<64, 256, 0, stream>>>(W_fc, Wfc_bf, 128 * 512 / 4);

  // phase A: context = relu(z_ctx_flat @ W_enc^T + b_enc)   (256 x 512, K=8192)
  gemm_bt<1><<<dim3(4, 8), 256, 0, stream>>>(zctx_bf, Wenc_bf, b_enc, context, 256, 512, 8192);
  // slow_input = [context | e]
  build_slow_kernel<<<640, 256, 0, stream>>>(context, e, slow_bf);
  // phase B: gi = slow_input @ W_ih^T + b_ih   (256 x 1536, K=640)
  gemm_bt<0><<<dim3(4, 24), 256, 0, stream>>>(slow_bf, Wih_bf, b_ih, gi, 256, 1536, 640);
  // phase C: sequential GRU scan, writes Hall
  gru_scan<<<16, 512, 0, stream>>>(gi, Whh_bf, b_hh, Hall);
  // phase D+E: FC + cumulative sum + transpose into out
  fc_scan<<<256, 256, 0, stream>>>(Hall, Wfc_bf, b_fc, z_ctx, out);
}

// Round 3
// 8029.739 us; speedup vs baseline: 2.5469x; 2.5469x over previous
//
#include <hip/hip_runtime.h>

// B=256, D=128, T=512, E=128, H=512, WH=512, WIN=64
typedef __attribute__((ext_vector_type(8))) short s8v;
typedef __attribute__((ext_vector_type(4))) float f4v;

#define MFMA16(a, b, c) __builtin_amdgcn_mfma_f32_16x16x32_bf16((a), (b), (c), 0, 0, 0)

__device__ __forceinline__ unsigned short f2bf(float f) {
  unsigned u = __float_as_uint(f);
  return (unsigned short)((u + 0x7fffu + ((u >> 16) & 1u)) >> 16);
}

// ---------- fp32 -> bf16 conversion (vectorized by 4) ----------
__global__ void cvt4_kernel(const float* __restrict__ in, unsigned short* __restrict__ out, int n4) {
  int i = blockIdx.x * blockDim.x + threadIdx.x;
  if (i >= n4) return;
  float4 v = ((const float4*)in)[i];
  ushort4 o;
  o.x = f2bf(v.x); o.y = f2bf(v.y); o.z = f2bf(v.z); o.w = f2bf(v.w);
  ((ushort4*)out)[i] = o;
}

// ---------- slow_input = [context | e] as bf16 (256 x 640) ----------
__global__ void build_slow_kernel(const float* __restrict__ context, const float* __restrict__ e,
                                  unsigned short* __restrict__ out) {
  int i = blockIdx.x * blockDim.x + threadIdx.x;
  if (i >= 256 * 640) return;
  int b = i / 640, c = i - b * 640;
  float v = (c < 512) ? context[b * 512 + c] : e[b * 128 + (c - 512)];
  out[i] = f2bf(v);
}

// ---------- generic GEMM: C[M][N] = act(A[M][K] @ B[N][K]^T + bias), bf16 in fp32 out ----------
template <int RELU>
__global__ __launch_bounds__(256) void gemm_bt(const unsigned short* __restrict__ A,
                                               const unsigned short* __restrict__ B,
                                               const float* __restrict__ bias, float* __restrict__ C,
                                               int M, int N, int K) {
  __shared__ unsigned short As[64][48];
  __shared__ unsigned short Bs[64][48];
  int tid = threadIdx.x;
  int lane = tid & 63, w = tid >> 6;
  int m = lane & 15, q = lane >> 4;
  int row0 = blockIdx.x * 64, col0 = blockIdx.y * 64;
  int sr = tid >> 2, sk = (tid & 3) * 8;
  const unsigned short* Ap = A + (size_t)(row0 + sr) * K + sk;
  const unsigned short* Bp = B + (size_t)(col0 + sr) * K + sk;
  f4v acc[4];
#pragma unroll
  for (int nt = 0; nt < 4; nt++) acc[nt] = (f4v){0.f, 0.f, 0.f, 0.f};

  for (int k0 = 0; k0 < K; k0 += 32) {
    *(uint4*)&As[sr][sk] = *(const uint4*)(Ap + k0);
    *(uint4*)&Bs[sr][sk] = *(const uint4*)(Bp + k0);
    __syncthreads();
    s8v a = *(const s8v*)&As[w * 16 + m][q * 8];
#pragma unroll
    for (int nt = 0; nt < 4; nt++) {
      s8v bb = *(const s8v*)&Bs[nt * 16 + m][q * 8];
      acc[nt] = MFMA16(a, bb, acc[nt]);
    }
    __syncthreads();
  }
#pragma unroll
  for (int nt = 0; nt < 4; nt++) {
    int c = col0 + nt * 16 + m;
    float bv = bias[c];
#pragma unroll
    for (int i = 0; i < 4; i++) {
      int r = row0 + w * 16 + q * 4 + i;
      float v = acc[nt][i] + bv;
      if (RELU) v = v > 0.f ? v : 0.f;
      C[(size_t)r * N + c] = v;
    }
  }
}

// ---------- phase C: distributed GRU scan ----------
// 512 WGs x 64 threads = 16 batch-groups (16 rows) x 32 col-groups (16 h-cols).
// W_hh slice (48 rows x 512) LDS-resident as MFMA A-fragments. h exchanged via Hall
// (agent-scope L3 ops). Per-step sync: per-batch-group arrival counters (one per t).
// Hall layout: [b][t][h=512] bf16 -> 128 u64 per (b,t).
__global__ __launch_bounds__(64) void gru_scan2(const float* __restrict__ gi,
                                                const unsigned short* __restrict__ Whh,
                                                const float* __restrict__ bhh,
                                                unsigned long long* __restrict__ Hall8,
                                                unsigned int* __restrict__ cnt) {
  __shared__ unsigned short wlds[3 * 16 * 64 * 8];  // 48 KB: [g][kc][lane][8]
  int tid = threadIdx.x;
  int bid = blockIdx.x;
  int bg = bid >> 5, cg = bid & 31;
  int b0 = bg * 16;
  int n = tid & 15, q = tid >> 4;

  // stage W slice into LDS in A-fragment order (one-time, 48 KB)
#pragma unroll 1
  for (int it = 0; it < 48; ++it) {
    int g = it >> 4, kc = it & 15;
    int row = g * 512 + cg * 16 + n;
    int kcol = kc * 32 + q * 8;
    *(uint4*)&wlds[(it * 64 + tid) * 8] = *(const uint4*)(Whh + (size_t)row * 512 + kcol);
  }

  // time-invariant gate inputs (gi includes b_ih; fold b_hh for r,z; keep n-gate separate)
  float gir[4], giz[4], gin[4], bhn[4];
#pragma unroll
  for (int i = 0; i < 4; ++i) {
    int c = cg * 16 + q * 4 + i;
    const float* gp = gi + (size_t)(b0 + n) * 1536 + c;
    gir[i] = gp[0] + bhh[c];
    giz[i] = gp[512] + bhh[c + 512];
    gin[i] = gp[1024];
    bhn[i] = bhh[c + 1024];
  }
  float hp[4] = {0.f, 0.f, 0.f, 0.f};
  __syncthreads();

  unsigned int* mycnt = cnt + bg * 512;
  size_t rowbase = (size_t)(b0 + n) * 512 * 128;     // 128 u64 per (b,t)
  size_t stoff = (size_t)cg * 4 + q;                 // (cg*16+q*4)/4

#pragma unroll 1
  for (int t = 0; t < 512; ++t) {
    f4v ar = {gir[0], gir[1], gir[2], gir[3]};
    f4v az = {giz[0], giz[1], giz[2], giz[3]};
    f4v an = {bhn[0], bhn[1], bhn[2], bhn[3]};
    if (t > 0) {
      // wait for all 32 col-groups to finish step t-1 (bailout turns deadlock into wrong answer)
      for (long sp = 0; sp < 500000L; ++sp) {
        if (__hip_atomic_load(mycnt + (t - 1), __ATOMIC_RELAXED, __HIP_MEMORY_SCOPE_AGENT) >= 32u)
          break;
      }
      __builtin_amdgcn_fence(__ATOMIC_ACQUIRE, "agent");
      unsigned long long* hp8 = Hall8 + rowbase + (size_t)(t - 1) * 128 + q * 2;
      s8v bf[16];
#pragma unroll
      for (int kc = 0; kc < 16; ++kc) {
        union { unsigned long long u[2]; s8v v; } uv;
        uv.u[0] = __hip_atomic_load(hp8 + kc * 8, __ATOMIC_RELAXED, __HIP_MEMORY_SCOPE_AGENT);
        uv.u[1] = __hip_atomic_load(hp8 + kc * 8 + 1, __ATOMIC_RELAXED, __HIP_MEMORY_SCOPE_AGENT);
        bf[kc] = uv.v;
      }
#pragma unroll
      for (int kc = 0; kc < 16; ++kc) {
        s8v a0 = *(const s8v*)&wlds[((0 * 16 + kc) * 64 + tid) * 8];
        ar = MFMA16(a0, bf[kc], ar);
        s8v a1 = *(const s8v*)&wlds[((1 * 16 + kc) * 64 + tid) * 8];
        az = MFMA16(a1, bf[kc], az);
        s8v a2 = *(const s8v*)&wlds[((2 * 16 + kc) * 64 + tid) * 8];
        an = MFMA16(a2, bf[kc], an);
      }
    }
    union { unsigned short s[4]; unsigned long long u; } pk;
#pragma unroll
    for (int i = 0; i < 4; ++i) {
      float r = 1.f / (1.f + __expf(-ar[i]));
      float zg = 1.f / (1.f + __expf(-az[i]));
      float x = gin[i] + r * an[i];
      float ex = __expf(2.f * x);
      float nn = 1.f - 2.f / (ex + 1.f);
      float h = (1.f - zg) * nn + zg * hp[i];
      hp[i] = h;
      pk.s[i] = f2bf(h);
    }
    __hip_atomic_store(Hall8 + rowbase + (size_t)t * 128 + stoff, pk.u,
                       __ATOMIC_RELAXED, __HIP_MEMORY_SCOPE_AGENT);
    if (tid == 0)
      __hip_atomic_fetch_add(mycnt + t, 1u, __ATOMIC_RELEASE, __HIP_MEMORY_SCOPE_AGENT);
  }
}

// ---------- phase D+E fused: inc = Hall @ Wfc^T + bfc; out[b,d,t] = zp0 + cumsum_t(inc) ----------
__global__ __launch_bounds__(256) void fc_scan(const unsigned short* __restrict__ Hall,
                                               const unsigned short* __restrict__ Wfc,
                                               const float* __restrict__ bfc,
                                               const float* __restrict__ zctx,
                                               float* __restrict__ out) {
  __shared__ unsigned short hs[16][520];
  int tid = threadIdx.x;
  int lane = tid & 63, w = tid >> 6;
  int m = lane & 15, q = lane >> 4;
  int b = blockIdx.x;

  s8v wf[2][16];
  float bf_r[2], carry[2];
#pragma unroll
  for (int j = 0; j < 2; j++) {
    int d = (2 * w + j) * 16 + m;
#pragma unroll
    for (int kc = 0; kc < 16; kc++)
      wf[j][kc] = *(const s8v*)(Wfc + (size_t)d * 512 + kc * 32 + q * 8);
    bf_r[j] = bfc[d];
    carry[j] = zctx[((size_t)b * 128 + d) * 64 + 63];
  }

#pragma unroll 1
  for (int chunk = 0; chunk < 32; chunk++) {
    int t0 = chunk * 16;
    {
      int mm = tid >> 4, ci = (tid & 15) * 4;
      const unsigned short* src = Hall + ((size_t)b * 512 + t0 + mm) * 512 + ci * 8;
#pragma unroll
      for (int o = 0; o < 4; o++) {
        uint4 v = *(const uint4*)(src + o * 8);
        *(uint4*)&hs[mm][(ci + o) * 8] = v;
      }
    }
    __syncthreads();
    s8v af[16];
#pragma unroll
    for (int kc = 0; kc < 16; kc++) af[kc] = *(const s8v*)&hs[m][kc * 32 + q * 8];
    f4v acc[2];
    acc[0] = (f4v){0.f, 0.f, 0.f, 0.f};
    acc[1] = (f4v){0.f, 0.f, 0.f, 0.f};
#pragma unroll
    for (int kc = 0; kc < 16; kc++) {
      acc[0] = MFMA16(af[kc], wf[0][kc], acc[0]);
      acc[1] = MFMA16(af[kc], wf[1][kc], acc[1]);
    }
    __syncthreads();

#pragma unroll
    for (int j = 0; j < 2; j++) {
      float s0 = acc[j][0] + bf_r[j];
      float s1 = s0 + acc[j][1] + bf_r[j];
      float s2 = s1 + acc[j][2] + bf_r[j];
      float s3 = s2 + acc[j][3] + bf_r[j];
      float tot = s3;
      float incl = tot;
      float u = __shfl_up(incl, 16, 64);
      if (q >= 1) incl += u;
      u = __shfl_up(incl, 32, 64);
      if (q >= 2) incl += u;
      float excl = incl - tot;
      float add = excl + carry[j];
      int d = (2 * w + j) * 16 + m;
      float4 o4 = make_float4(s0 + add, s1 + add, s2 + add, s3 + add);
      *(float4*)(out + ((size_t)b * 128 + d) * 512 + t0 + q * 4) = o4;
      float chunktot = __shfl(incl, 48 + m, 64);
      carry[j] += chunktot;
    }
  }
}

extern "C" void kernel_launch(void* const* d_in, const int* in_sizes, int n_in,
                              void* d_out, int out_size, void* d_ws, size_t ws_size,
                              hipStream_t stream) {
  const float* z_ctx = (const float*)d_in[0];
  const float* e     = (const float*)d_in[4];
  const float* W_enc = (const float*)d_in[5];
  const float* b_enc = (const float*)d_in[6];
  const float* W_ih  = (const float*)d_in[7];
  const float* W_hh  = (const float*)d_in[8];
  const float* b_ih  = (const float*)d_in[9];
  const float* b_hh  = (const float*)d_in[10];
  const float* W_fc  = (const float*)d_in[11];
  const float* b_fc  = (const float*)d_in[12];
  float* out = (float*)d_out;

  char* ws = (char*)d_ws;
  const size_t OFF_WENC = 0;          // 512*8192*2
  const size_t OFF_ZCTX = 8388608;    // 256*8192*2
  const size_t OFF_WIH  = 12582912;   // 1536*640*2
  const size_t OFF_WHH  = 14548992;   // 1536*512*2
  const size_t OFF_WFC  = 16121856;   // 128*512*2
  const size_t OFF_CTX  = 16252928;   // 256*512*4
  const size_t OFF_SLOW = 16777216;   // 256*640*2
  const size_t OFF_GI   = 17104896;   // 256*1536*4
  const size_t OFF_HALL = 18677760;   // 256*512*512*2
  const size_t OFF_CNT  = OFF_HALL + 134217728ull;  // 16*512*4 = 32768
  const size_t NEED = OFF_CNT + 32768;
  if (ws_size < NEED) return;

  unsigned short* Wenc_bf = (unsigned short*)(ws + OFF_WENC);
  unsigned short* zctx_bf = (unsigned short*)(ws + OFF_ZCTX);
  unsigned short* Wih_bf  = (unsigned short*)(ws + OFF_WIH);
  unsigned short* Whh_bf  = (unsigned short*)(ws + OFF_WHH);
  unsigned short* Wfc_bf  = (unsigned short*)(ws + OFF_WFC);
  float* context          = (float*)(ws + OFF_CTX);
  unsigned short* slow_bf = (unsigned short*)(ws + OFF_SLOW);
  float* gi               = (float*)(ws + OFF_GI);
  unsigned short* Hall    = (unsigned short*)(ws + OFF_HALL);
  unsigned long long* Hall8 = (unsigned long long*)(ws + OFF_HALL);
  unsigned int* cnt       = (unsigned int*)(ws + OFF_CNT);

  hipMemsetAsync(cnt, 0, 32768, stream);

  cvt4_kernel<<<4096, 256, 0, stream>>>(W_enc, Wenc_bf, 512 * 8192 / 4);
  cvt4_kernel<<<2048, 256, 0, stream>>>(z_ctx, zctx_bf, 256 * 8192 / 4);
  cvt4_kernel<<<960, 256, 0, stream>>>(W_ih, Wih_bf, 1536 * 640 / 4);
  cvt4_kernel<<<768, 256, 0, stream>>>(W_hh, Whh_bf, 1536 * 512 / 4);
  cvt4_kernel<<<64, 256, 0, stream>>>(W_fc, Wfc_bf, 128 * 512 / 4);

  gemm_bt<1><<<dim3(4, 8), 256, 0, stream>>>(zctx_bf, Wenc_bf, b_enc, context, 256, 512, 8192);
  build_slow_kernel<<<640, 256, 0, stream>>>(context, e, slow_bf);
  gemm_bt<0><<<dim3(4, 24), 256, 0, stream>>>(slow_bf, Wih_bf, b_ih, gi, 256, 1536, 640);

  // distributed GRU scan — cooperative launch guarantees all 512 WGs co-resident;
  // fall back to a regular launch (512 <= 768-block capacity at 48 KB LDS) if unavailable.
  {
    const float* gi_c = gi;
    const unsigned short* whh_c = Whh_bf;
    const float* bhh_c = b_hh;
    unsigned long long* hall_c = Hall8;
    unsigned int* cnt_c = cnt;
    void* args[] = {(void*)&gi_c, (void*)&whh_c, (void*)&bhh_c, (void*)&hall_c, (void*)&cnt_c};
    hipError_t err = hipLaunchCooperativeKernel((void*)gru_scan2, dim3(512), dim3(64), args, 0, stream);
    if (err != hipSuccess) {
      gru_scan2<<<512, 64, 0, stream>>>(gi, Whh_bf, b_hh, Hall8, cnt);
    }
  }

  fc_scan<<<256, 256, 0, stream>>>(Hall, Wfc_bf, b_fc, z_ctx, out);
}